// Round 5
// baseline (1015.841 us; speedup 1.0000x reference)
//
#include <hip/hip_runtime.h>
#include <math.h>

#define TPB 512
#define TPB_R 512
#define BUCKET_SHIFT 11
#define BUCKET_SIZE 2048            // nodes per reduction bucket (11 bits local)
#define MAX_NB 1024                 // max buckets supported by fast path
#define TILE 32768                  // edges per tile in hist/bin kernels
#define SUB 8192                    // edges per sub-chunk inside bin kernel
#define SRC_BITS 20
#define SRC_MASK ((1u << SRC_BITS) - 1u)
#define LOC_MASK ((unsigned)(BUCKET_SIZE - 1))
#define SPLIT 4                     // blocks cooperating per bucket in reduce

// native clang vector types: required by __builtin_nontemporal_load
typedef int          int4n   __attribute__((ext_vector_type(4)));
typedef unsigned int uint4n  __attribute__((ext_vector_type(4)));
typedef float        float4n __attribute__((ext_vector_type(4)));

// ---------- scan helpers ----------

__device__ inline unsigned wave_scan_incl(unsigned v) {
#pragma unroll
    for (int d = 1; d < 64; d <<= 1) {
        unsigned n = __shfl_up(v, d, 64);
        if ((int)(threadIdx.x & 63) >= d) v += n;
    }
    return v;
}

__device__ inline void block_excl_scan_1024(unsigned a0, unsigned a1,
                                            unsigned* wtot,
                                            unsigned& e0, unsigned& e1) {
    unsigned s = a0 + a1;
    unsigned incl = wave_scan_incl(s);
    int lane = threadIdx.x & 63, wid = threadIdx.x >> 6;  // 8 waves
    if (lane == 63) wtot[wid] = incl;
    __syncthreads();
    if (threadIdx.x == 0) {
        unsigned c = 0;
#pragma unroll
        for (int i = 0; i < 8; ++i) { unsigned tv = wtot[i]; wtot[i] = c; c += tv; }
    }
    __syncthreads();
    unsigned base = wtot[wid] + incl - s;
    e0 = base;
    e1 = base + a0;
}

// ---------- K1: per-tile bucket histogram (per-wave privatized) ----------

__global__ __launch_bounds__(TPB)
void hist_kernel(const int* __restrict__ dst, unsigned* __restrict__ counts,
                 long long E, int NB, int G) {
    __shared__ unsigned hist[8 * MAX_NB];   // 8 waves x 1024 buckets = 32 KB
    int g = blockIdx.x, t = threadIdx.x;
    for (int i = t; i < 8 * MAX_NB; i += TPB) hist[i] = 0;
    __syncthreads();
    int wid = t >> 6;
    unsigned* h = hist + (wid << 10);
    long long start = (long long)g * TILE;
    long long end = start + TILE; if (end > E) end = E;
    long long nfull4 = (end - start) >> 2;
    const int4n* d4 = (const int4n*)(dst + start);
    for (long long v = t; v < nfull4; v += TPB) {
        int4n d = __builtin_nontemporal_load(d4 + v);
        atomicAdd(&h[((unsigned)d.x) >> BUCKET_SHIFT], 1u);
        atomicAdd(&h[((unsigned)d.y) >> BUCKET_SHIFT], 1u);
        atomicAdd(&h[((unsigned)d.z) >> BUCKET_SHIFT], 1u);
        atomicAdd(&h[((unsigned)d.w) >> BUCKET_SHIFT], 1u);
    }
    for (long long e = start + nfull4 * 4 + t; e < end; e += TPB)
        atomicAdd(&h[((unsigned)dst[e]) >> BUCKET_SHIFT], 1u);
    __syncthreads();
    for (int b = t; b < NB; b += TPB) {
        unsigned c = 0;
#pragma unroll
        for (int w = 0; w < 8; ++w) c += hist[(w << 10) + b];
        counts[(size_t)b * G + g] = c;
    }
}

// ---------- K2a: exclusive scan of each bucket row (over tiles) ----------

__global__ __launch_bounds__(TPB)
void scan_rows(unsigned* __restrict__ counts, unsigned* __restrict__ rowTotal,
               int G) {
    __shared__ unsigned wtot[8];
    int b = blockIdx.x, t = threadIdx.x;
    int g0 = 2 * t, g1 = 2 * t + 1;
    unsigned a0 = (g0 < G) ? counts[(size_t)b * G + g0] : 0u;
    unsigned a1 = (g1 < G) ? counts[(size_t)b * G + g1] : 0u;
    unsigned e0, e1;
    block_excl_scan_1024(a0, a1, wtot, e0, e1);
    if (g0 < G) counts[(size_t)b * G + g0] = e0;
    if (g1 < G) counts[(size_t)b * G + g1] = e1;
    if (t == TPB - 1) rowTotal[b] = e1 + a1;
}

// ---------- K2b: exclusive scan of bucket totals ----------

__global__ __launch_bounds__(TPB)
void scan_buckets(const unsigned* __restrict__ rowTotal,
                  unsigned* __restrict__ bucketStart, int NB) {
    __shared__ unsigned wtot[8];
    int t = threadIdx.x;
    int b0 = 2 * t, b1 = 2 * t + 1;
    unsigned a0 = (b0 < NB) ? rowTotal[b0] : 0u;
    unsigned a1 = (b1 < NB) ? rowTotal[b1] : 0u;
    unsigned e0, e1;
    block_excl_scan_1024(a0, a1, wtot, e0, e1);
    if (b0 <= NB) bucketStart[b0] = e0;
    if (b1 <= NB) bucketStart[b1] = e1;
}

// ---------- K3: tile-local counting sort -> packed (+ optional x-value fill) ----------

__global__ __launch_bounds__(TPB)
void bin_kernel(const int* __restrict__ src, const int* __restrict__ dst,
                const unsigned* __restrict__ counts,
                const unsigned* __restrict__ bucketStart,
                unsigned* __restrict__ packed,
                const float* __restrict__ x, float* __restrict__ xval,
                int writeVals, long long E, int NB, int G) {
    __shared__ unsigned cursor[MAX_NB];
    __shared__ unsigned A[MAX_NB];
    __shared__ unsigned B[MAX_NB];
    __shared__ unsigned wtot[8];
    __shared__ unsigned short sKey[SUB];
    __shared__ unsigned sPack[SUB];
    int g = blockIdx.x, t = threadIdx.x;

    for (int b = t; b < MAX_NB; b += TPB)
        cursor[b] = (b < NB) ? (bucketStart[b] + counts[(size_t)b * G + g]) : 0u;

    long long tileStart = (long long)g * TILE;
    long long tileEnd = tileStart + TILE; if (tileEnd > E) tileEnd = E;

    for (long long subBase = tileStart; subBase < tileEnd; subBase += SUB) {
        long long rem = tileEnd - subBase;
        int subCount = (rem < (long long)SUB) ? (int)rem : SUB;

        for (int b = t; b < MAX_NB; b += TPB) A[b] = 0u;
        __syncthreads();

        unsigned key[16], pk[16];
#pragma unroll
        for (int r = 0; r < 4; ++r) {
            long long ebase = subBase + ((long long)(r * TPB + t)) * 4;
            int4n sv = (int4n)0, dv = (int4n)0;
            if (ebase + 4 <= tileEnd) {
                sv = __builtin_nontemporal_load((const int4n*)(src + ebase));
                dv = __builtin_nontemporal_load((const int4n*)(dst + ebase));
            } else if (ebase < tileEnd) {
                int n = (int)(tileEnd - ebase);
                const int* sp = src + ebase;
                const int* dp = dst + ebase;
                sv.x = sp[0]; dv.x = dp[0];
                if (n > 1) { sv.y = sp[1]; dv.y = dp[1]; }
                if (n > 2) { sv.z = sp[2]; dv.z = dp[2]; }
            }
            long long navail = tileEnd - ebase;
            int n = (navail < 0) ? 0 : ((navail > 4) ? 4 : (int)navail);
            unsigned dd[4] = {(unsigned)dv.x, (unsigned)dv.y, (unsigned)dv.z, (unsigned)dv.w};
            unsigned ss[4] = {(unsigned)sv.x, (unsigned)sv.y, (unsigned)sv.z, (unsigned)sv.w};
#pragma unroll
            for (int c = 0; c < 4; ++c) {
                int j = r * 4 + c;
                if (c < n) {
                    unsigned k = dd[c] >> BUCKET_SHIFT;
                    key[j] = k;
                    pk[j] = ((dd[c] & LOC_MASK) << SRC_BITS) | ss[c];
                    atomicAdd(&A[k], 1u);
                } else {
                    key[j] = 0xFFFFFFFFu;
                    pk[j] = 0u;
                }
            }
        }
        __syncthreads();

        unsigned a0 = A[2 * t], a1 = A[2 * t + 1];
        unsigned e0, e1;
        block_excl_scan_1024(a0, a1, wtot, e0, e1);
        A[2 * t] = e0; A[2 * t + 1] = e1;
        B[2 * t] = e0; B[2 * t + 1] = e1;
        __syncthreads();

#pragma unroll
        for (int j = 0; j < 16; ++j) {
            if (key[j] != 0xFFFFFFFFu) {
                unsigned r = atomicAdd(&B[key[j]], 1u);
                sKey[r] = (unsigned short)key[j];
                sPack[r] = pk[j];
            }
        }
        __syncthreads();

        if (writeVals) {
            // scatter + layer-1 value gather fused: the random x[src] reads
            // overlap this kernel's LDS work instead of costing a kernel.
            for (int base = t; base < subCount; base += 4 * TPB) {
                unsigned pks[4]; unsigned bks[4]; float vs[4]; int jjs[4]; int valid[4];
#pragma unroll
                for (int r = 0; r < 4; ++r) {
                    int jj = base + r * TPB;
                    valid[r] = (jj < subCount);
                    jjs[r] = jj;
                    if (valid[r]) { bks[r] = sKey[jj]; pks[r] = sPack[jj]; }
                }
#pragma unroll
                for (int r = 0; r < 4; ++r)
                    if (valid[r]) vs[r] = x[pks[r] & SRC_MASK];
#pragma unroll
                for (int r = 0; r < 4; ++r) {
                    if (valid[r]) {
                        unsigned b = bks[r];
                        unsigned gpos = cursor[b] + (unsigned)jjs[r] - A[b];
                        packed[gpos] = pks[r];
                        xval[gpos] = vs[r];
                    }
                }
            }
        } else {
            for (int jj = t; jj < subCount; jj += TPB) {
                unsigned b = sKey[jj];
                unsigned gpos = cursor[b] + (unsigned)jj - A[b];
                packed[gpos] = sPack[jj];
            }
        }
        __syncthreads();

        for (int b = t; b < NB; b += TPB) {
            unsigned nextA = (b + 1 < MAX_NB) ? A[b + 1] : (unsigned)subCount;
            cursor[b] += nextA - A[b];
        }
        __syncthreads();
    }
}

// ---------- K4a: streaming reduce (values pre-gathered), SPLIT blocks/bucket ----------

__global__ __launch_bounds__(TPB_R)
void reduce_stream_split(const unsigned* __restrict__ packed,
                         const float* __restrict__ xval,
                         const unsigned* __restrict__ bucketStart,
                         float* __restrict__ part) {
    __shared__ float acc[BUCKET_SIZE];
    int blk = blockIdx.x, t = threadIdx.x;
    int b = blk / SPLIT, s = blk % SPLIT;
    for (int k = t; k < BUCKET_SIZE; k += TPB_R) acc[k] = 0.f;
    __syncthreads();
    unsigned s0 = bucketStart[b], e0 = bucketStart[b + 1];
    unsigned len = e0 - s0;
    unsigned chunk = (len + SPLIT - 1) / SPLIT;
    unsigned beg = s0 + (unsigned)s * chunk;
    unsigned end = beg + chunk;
    if (beg > e0) beg = e0;
    if (end > e0) end = e0;
    if (beg < end) {
        unsigned cnt = end - beg;
        unsigned head = (4u - (beg & 3u)) & 3u; if (head > cnt) head = cnt;
        if ((unsigned)t < head) {
            unsigned p = packed[beg + (unsigned)t];
            atomicAdd(&acc[p >> SRC_BITS], xval[beg + (unsigned)t]);
        }
        unsigned base4 = beg + head;
        unsigned n4 = (end - base4) >> 2;
        const uint4n* p4 = (const uint4n*)(packed + base4);
        const float4n* v4 = (const float4n*)(xval + base4);
        unsigned i = (unsigned)t;
        for (; i + 3u * TPB_R < n4; i += 4u * TPB_R) {
            uint4n q0 = __builtin_nontemporal_load(p4 + i);
            uint4n q1 = __builtin_nontemporal_load(p4 + i + TPB_R);
            uint4n q2 = __builtin_nontemporal_load(p4 + i + 2u * TPB_R);
            uint4n q3 = __builtin_nontemporal_load(p4 + i + 3u * TPB_R);
            float4n f0 = __builtin_nontemporal_load(v4 + i);
            float4n f1 = __builtin_nontemporal_load(v4 + i + TPB_R);
            float4n f2 = __builtin_nontemporal_load(v4 + i + 2u * TPB_R);
            float4n f3 = __builtin_nontemporal_load(v4 + i + 3u * TPB_R);
            atomicAdd(&acc[q0.x >> SRC_BITS], f0.x);
            atomicAdd(&acc[q0.y >> SRC_BITS], f0.y);
            atomicAdd(&acc[q0.z >> SRC_BITS], f0.z);
            atomicAdd(&acc[q0.w >> SRC_BITS], f0.w);
            atomicAdd(&acc[q1.x >> SRC_BITS], f1.x);
            atomicAdd(&acc[q1.y >> SRC_BITS], f1.y);
            atomicAdd(&acc[q1.z >> SRC_BITS], f1.z);
            atomicAdd(&acc[q1.w >> SRC_BITS], f1.w);
            atomicAdd(&acc[q2.x >> SRC_BITS], f2.x);
            atomicAdd(&acc[q2.y >> SRC_BITS], f2.y);
            atomicAdd(&acc[q2.z >> SRC_BITS], f2.z);
            atomicAdd(&acc[q2.w >> SRC_BITS], f2.w);
            atomicAdd(&acc[q3.x >> SRC_BITS], f3.x);
            atomicAdd(&acc[q3.y >> SRC_BITS], f3.y);
            atomicAdd(&acc[q3.z >> SRC_BITS], f3.z);
            atomicAdd(&acc[q3.w >> SRC_BITS], f3.w);
        }
        for (; i < n4; i += TPB_R) {
            uint4n q = __builtin_nontemporal_load(p4 + i);
            float4n f = __builtin_nontemporal_load(v4 + i);
            atomicAdd(&acc[q.x >> SRC_BITS], f.x);
            atomicAdd(&acc[q.y >> SRC_BITS], f.y);
            atomicAdd(&acc[q.z >> SRC_BITS], f.z);
            atomicAdd(&acc[q.w >> SRC_BITS], f.w);
        }
        for (unsigned j = base4 + n4 * 4u + (unsigned)t; j < end; j += TPB_R) {
            unsigned p = packed[j];
            atomicAdd(&acc[p >> SRC_BITS], xval[j]);
        }
    }
    __syncthreads();
    for (int k = t; k < BUCKET_SIZE; k += TPB_R)
        part[(size_t)blk * BUCKET_SIZE + k] = acc[k];
}

// ---------- K4b: gather reduce (random in[] reads), SPLIT blocks/bucket ----------

__global__ __launch_bounds__(TPB_R)
void reduce_gather_split(const unsigned* __restrict__ packed,
                         const unsigned* __restrict__ bucketStart,
                         const float* __restrict__ in,
                         float* __restrict__ part) {
    __shared__ float acc[BUCKET_SIZE];
    int blk = blockIdx.x, t = threadIdx.x;
    int b = blk / SPLIT, s = blk % SPLIT;
    for (int k = t; k < BUCKET_SIZE; k += TPB_R) acc[k] = 0.f;
    __syncthreads();
    unsigned s0 = bucketStart[b], e0 = bucketStart[b + 1];
    unsigned len = e0 - s0;
    unsigned chunk = (len + SPLIT - 1) / SPLIT;
    unsigned beg = s0 + (unsigned)s * chunk;
    unsigned end = beg + chunk;
    if (beg > e0) beg = e0;
    if (end > e0) end = e0;
    if (beg < end) {
        unsigned cnt = end - beg;
        unsigned head = (4u - (beg & 3u)) & 3u; if (head > cnt) head = cnt;
        if ((unsigned)t < head) {
            unsigned p = packed[beg + (unsigned)t];
            atomicAdd(&acc[p >> SRC_BITS], fmaxf(in[p & SRC_MASK], 0.f));
        }
        unsigned base4 = beg + head;
        unsigned n4 = (end - base4) >> 2;
        const uint4n* p4 = (const uint4n*)(packed + base4);
        unsigned i = (unsigned)t;
        for (; i + 3u * TPB_R < n4; i += 4u * TPB_R) {
            uint4n q0 = __builtin_nontemporal_load(p4 + i);
            uint4n q1 = __builtin_nontemporal_load(p4 + i + TPB_R);
            uint4n q2 = __builtin_nontemporal_load(p4 + i + 2u * TPB_R);
            uint4n q3 = __builtin_nontemporal_load(p4 + i + 3u * TPB_R);
            float v0  = fmaxf(in[q0.x & SRC_MASK], 0.f);
            float v1  = fmaxf(in[q0.y & SRC_MASK], 0.f);
            float v2  = fmaxf(in[q0.z & SRC_MASK], 0.f);
            float v3  = fmaxf(in[q0.w & SRC_MASK], 0.f);
            float v4  = fmaxf(in[q1.x & SRC_MASK], 0.f);
            float v5  = fmaxf(in[q1.y & SRC_MASK], 0.f);
            float v6  = fmaxf(in[q1.z & SRC_MASK], 0.f);
            float v7  = fmaxf(in[q1.w & SRC_MASK], 0.f);
            float v8  = fmaxf(in[q2.x & SRC_MASK], 0.f);
            float v9  = fmaxf(in[q2.y & SRC_MASK], 0.f);
            float v10 = fmaxf(in[q2.z & SRC_MASK], 0.f);
            float v11 = fmaxf(in[q2.w & SRC_MASK], 0.f);
            float v12 = fmaxf(in[q3.x & SRC_MASK], 0.f);
            float v13 = fmaxf(in[q3.y & SRC_MASK], 0.f);
            float v14 = fmaxf(in[q3.z & SRC_MASK], 0.f);
            float v15 = fmaxf(in[q3.w & SRC_MASK], 0.f);
            atomicAdd(&acc[q0.x >> SRC_BITS], v0);
            atomicAdd(&acc[q0.y >> SRC_BITS], v1);
            atomicAdd(&acc[q0.z >> SRC_BITS], v2);
            atomicAdd(&acc[q0.w >> SRC_BITS], v3);
            atomicAdd(&acc[q1.x >> SRC_BITS], v4);
            atomicAdd(&acc[q1.y >> SRC_BITS], v5);
            atomicAdd(&acc[q1.z >> SRC_BITS], v6);
            atomicAdd(&acc[q1.w >> SRC_BITS], v7);
            atomicAdd(&acc[q2.x >> SRC_BITS], v8);
            atomicAdd(&acc[q2.y >> SRC_BITS], v9);
            atomicAdd(&acc[q2.z >> SRC_BITS], v10);
            atomicAdd(&acc[q2.w >> SRC_BITS], v11);
            atomicAdd(&acc[q3.x >> SRC_BITS], v12);
            atomicAdd(&acc[q3.y >> SRC_BITS], v13);
            atomicAdd(&acc[q3.z >> SRC_BITS], v14);
            atomicAdd(&acc[q3.w >> SRC_BITS], v15);
        }
        for (; i < n4; i += TPB_R) {
            uint4n q = __builtin_nontemporal_load(p4 + i);
            float v0 = fmaxf(in[q.x & SRC_MASK], 0.f);
            float v1 = fmaxf(in[q.y & SRC_MASK], 0.f);
            float v2 = fmaxf(in[q.z & SRC_MASK], 0.f);
            float v3 = fmaxf(in[q.w & SRC_MASK], 0.f);
            atomicAdd(&acc[q.x >> SRC_BITS], v0);
            atomicAdd(&acc[q.y >> SRC_BITS], v1);
            atomicAdd(&acc[q.z >> SRC_BITS], v2);
            atomicAdd(&acc[q.w >> SRC_BITS], v3);
        }
        for (unsigned j = base4 + n4 * 4u + (unsigned)t; j < end; j += TPB_R) {
            unsigned p = packed[j];
            atomicAdd(&acc[p >> SRC_BITS], fmaxf(in[p & SRC_MASK], 0.f));
        }
    }
    __syncthreads();
    for (int k = t; k < BUCKET_SIZE; k += TPB_R)
        part[(size_t)blk * BUCKET_SIZE + k] = acc[k];
}

// ---------- K5: combine SPLIT partials, optional sigmoid ----------

__global__ __launch_bounds__(TPB_R)
void combine_kernel(const float* __restrict__ part, float* __restrict__ out,
                    int N, int act) {
    int b = blockIdx.x, t = threadIdx.x;
    for (int k = t; k < BUCKET_SIZE; k += TPB_R) {
        int node = b * BUCKET_SIZE + k;
        if (node < N) {
            float v = 0.f;
#pragma unroll
            for (int s = 0; s < SPLIT; ++s)
                v += part[(size_t)(b * SPLIT + s) * BUCKET_SIZE + k];
            out[node] = act ? 1.f / (1.f + expf(-v)) : v;
        }
    }
}

// ---------- round-4 direct reduce (ws-constrained fallback tier) ----------

__global__ __launch_bounds__(TPB_R)
void reduce_direct(const unsigned* __restrict__ packed,
                   const unsigned* __restrict__ bucketStart,
                   const float* __restrict__ in, float* __restrict__ out,
                   int N, int final_layer) {
    __shared__ float acc[BUCKET_SIZE];
    int b = blockIdx.x, t = threadIdx.x;
    for (int k = t; k < BUCKET_SIZE; k += TPB_R) acc[k] = 0.f;
    __syncthreads();
    unsigned s = bucketStart[b], e = bucketStart[b + 1];
    for (unsigned j = s + (unsigned)t; j < e; j += TPB_R) {
        unsigned p = packed[j];
        atomicAdd(&acc[p >> SRC_BITS], fmaxf(in[p & SRC_MASK], 0.f));
    }
    __syncthreads();
    for (int k = t; k < BUCKET_SIZE; k += TPB_R) {
        int node = b * BUCKET_SIZE + k;
        if (node < N) {
            float v = acc[k];
            out[node] = final_layer ? 1.f / (1.f + expf(-v)) : v;
        }
    }
}

// ---------- fallback (round-1 atomic path) ----------

__global__ void scatter_add_relu(const int* __restrict__ src,
                                 const int* __restrict__ dst,
                                 const float* __restrict__ in,
                                 float* __restrict__ out,
                                 long long E, long long E4) {
    long long i = (long long)blockIdx.x * blockDim.x + threadIdx.x;
    long long stride = (long long)gridDim.x * blockDim.x;
    const int4* src4 = (const int4*)src;
    const int4* dst4 = (const int4*)dst;
    for (long long v = i; v < E4; v += stride) {
        int4 s = src4[v];
        int4 d = dst4[v];
        atomicAdd(&out[d.x], fmaxf(in[s.x], 0.0f));
        atomicAdd(&out[d.y], fmaxf(in[s.y], 0.0f));
        atomicAdd(&out[d.z], fmaxf(in[s.z], 0.0f));
        atomicAdd(&out[d.w], fmaxf(in[s.w], 0.0f));
    }
    for (long long e = E4 * 4 + i; e < E; e += stride)
        atomicAdd(&out[dst[e]], fmaxf(in[src[e]], 0.0f));
}

__global__ void sigmoid_inplace(float* __restrict__ out, int n) {
    int i = blockIdx.x * blockDim.x + threadIdx.x;
    if (i < n) {
        float v = out[i];
        out[i] = 1.0f / (1.0f + expf(-v));
    }
}

// ---------- launch ----------

extern "C" void kernel_launch(void* const* d_in, const int* in_sizes, int n_in,
                              void* d_out, int out_size, void* d_ws, size_t ws_size,
                              hipStream_t stream) {
    const float* x = (const float*)d_in[0];
    const int* ei = (const int*)d_in[1];
    const int N = in_sizes[0];
    const long long E = (long long)in_sizes[1] / 2;
    const int* src = ei;
    const int* dst = ei + E;
    float* out = (float*)d_out;

    const int NB = (N + BUCKET_SIZE - 1) / BUCKET_SIZE;
    const int G = (int)((E + TILE - 1) / TILE);

    size_t off = 0;
    auto alloc = [&](size_t bytes) {
        size_t o = off;
        off = (off + bytes + 255) & ~(size_t)255;
        return o;
    };
    char* ws = (char*)d_ws;
    size_t countsOff = alloc((size_t)NB * (size_t)G * 4);
    size_t rowTotOff = alloc((size_t)NB * 4);
    size_t bsOff     = alloc((size_t)(NB + 1) * 4);
    size_t h1Off     = alloc((size_t)N * 4);
    size_t packedOff = alloc((size_t)E * 4);
    size_t baseEnd   = off;
    size_t partOff   = alloc((size_t)NB * SPLIT * BUCKET_SIZE * 4);
    size_t partEnd   = off;
    size_t xvalOff   = alloc((size_t)E * 4);
    size_t fullEnd   = off;

    const bool shapeOK = (N <= (1 << SRC_BITS)) && (NB <= MAX_NB) && (G <= 2 * TPB);
    const int tier = !shapeOK ? 3 :
                     (fullEnd <= ws_size) ? 0 :
                     (partEnd <= ws_size) ? 1 :
                     (baseEnd <= ws_size) ? 2 : 3;

    if (tier <= 2) {
        unsigned* counts = (unsigned*)(ws + countsOff);
        unsigned* rowTot = (unsigned*)(ws + rowTotOff);
        unsigned* bstart = (unsigned*)(ws + bsOff);
        float*    h1     = (float*)(ws + h1Off);
        unsigned* packed = (unsigned*)(ws + packedOff);
        float*    part   = (float*)(ws + partOff);
        float*    xval   = (float*)(ws + xvalOff);

        hist_kernel<<<G, TPB, 0, stream>>>(dst, counts, E, NB, G);
        scan_rows<<<NB, TPB, 0, stream>>>(counts, rowTot, G);
        scan_buckets<<<1, TPB, 0, stream>>>(rowTot, bstart, NB);
        bin_kernel<<<G, TPB, 0, stream>>>(src, dst, counts, bstart, packed,
                                          x, xval, (tier == 0) ? 1 : 0, E, NB, G);
        if (tier == 0) {
            // layer 1: pure streaming (values pre-gathered in bin)
            reduce_stream_split<<<NB * SPLIT, TPB_R, 0, stream>>>(packed, xval, bstart, part);
            combine_kernel<<<NB, TPB_R, 0, stream>>>(part, h1, N, 0);
            // layer 2: gather from h1
            reduce_gather_split<<<NB * SPLIT, TPB_R, 0, stream>>>(packed, bstart, h1, part);
            combine_kernel<<<NB, TPB_R, 0, stream>>>(part, out, N, 1);
        } else if (tier == 1) {
            reduce_gather_split<<<NB * SPLIT, TPB_R, 0, stream>>>(packed, bstart, x, part);
            combine_kernel<<<NB, TPB_R, 0, stream>>>(part, h1, N, 0);
            reduce_gather_split<<<NB * SPLIT, TPB_R, 0, stream>>>(packed, bstart, h1, part);
            combine_kernel<<<NB, TPB_R, 0, stream>>>(part, out, N, 1);
        } else {
            reduce_direct<<<NB, TPB_R, 0, stream>>>(packed, bstart, x, h1, N, 0);
            reduce_direct<<<NB, TPB_R, 0, stream>>>(packed, bstart, h1, out, N, 1);
        }
    } else {
        float* h1 = (float*)ws;
        (void)hipMemsetAsync(h1, 0, (size_t)N * sizeof(float), stream);
        (void)hipMemsetAsync(out, 0, (size_t)N * sizeof(float), stream);
        const long long E4 = ((E & 3) == 0) ? (E >> 2) : 0;
        const long long work = (E4 > 0) ? E4 : E;
        long long blocks_ll = (work + 255) / 256;
        if (blocks_ll > 131072) blocks_ll = 131072;
        const int blocks = (int)blocks_ll;
        scatter_add_relu<<<blocks, 256, 0, stream>>>(src, dst, x, h1, E, E4);
        scatter_add_relu<<<blocks, 256, 0, stream>>>(src, dst, h1, out, E, E4);
        sigmoid_inplace<<<(N + 255) / 256, 256, 0, stream>>>(out, N);
    }
}